// Round 7
// baseline (1664.440 us; speedup 1.0000x reference)
//
#include <hip/hip_runtime.h>

// RLIF forward, persistent kernel, stamped-qword sync with wide coherent reads.
// Round 7 vs round 6 (PASS @1354us): sync message format only; datapath frozen.
// - Publish: 16x atomicExch(u64) per wg per step: (t<<32)|row(2p+1)<<16|row(2p).
// - Consume: optimistic global_load_dwordx4 sc0 sc1 (4B-granule atomicity is
//   enough: each qword self-stamped), verify stamps, scalar 8B atomic re-poll
//   for stragglers only. Cuts steady-state poll transactions ~16x (524K -> 131K).
// - MFMA chain / epilogue / ys contents bit-identical to rounds 5/6.

#define T_STEPS 256
#define BATCH   128
#define NNEUR   1024
#define DECAY_F 0.2f
#define THRESH  0.3f

typedef __attribute__((ext_vector_type(8))) short short8;
typedef __attribute__((ext_vector_type(4))) float f32x4;
typedef __attribute__((ext_vector_type(4))) unsigned uint4v;

union FU { short8 s; unsigned u[4]; };

__device__ __forceinline__ unsigned short f2bf_rn(float x) {
    unsigned u = __float_as_uint(x);
    return (unsigned short)((u + 0x7FFFu + ((u >> 16) & 1u)) >> 16);
}

__global__ void rlif_init(unsigned long long* __restrict__ qbuf) {
    int i = blockIdx.x * 256 + threadIdx.x;
    if (i < 3 * 64 * 64) qbuf[i] = 0xFFFFFFFF00000000ull;  // stamp never matches t
}

__global__ __launch_bounds__(256, 1)
void rlif_persist(const float* __restrict__ tx,   // [T][B][N]
                  const float* __restrict__ Wr,   // [N][N]
                  const float* __restrict__ br,   // [N]
                  float* __restrict__ out,        // [T][B][N]
                  unsigned long long* __restrict__ qbuf) // [3][64 pairs][64 cols]
{
    extern __shared__ char smem[];
    unsigned short* wlds = (unsigned short*)smem;        // 3 * [16][1024] bf16, swizzled
    float* red = (float*)(smem + 3 * 16 * 1024 * 2);     // [2][16][16] f32 k-reduce
    unsigned short* ys = (unsigned short*)(smem + 3 * 16 * 1024 * 2 + 2 * 16 * 16 * 4); // [32][66]

    const int tid = threadIdx.x;
    const int bb  = blockIdx.x >> 6;   // 0..3  batch-block (32 batches)
    const int ib  = blockIdx.x & 63;   // 0..63 neuron-block (16 neurons)
    const int i0  = ib * 16;
    const int b0  = bb * 32;
    const int w   = tid >> 6;          // wave 0..3
    const int l   = tid & 63;
    const int c   = l & 15;
    const int kg  = l >> 4;
    const int r   = w & 1;             // row-tile
    const int h   = w >> 1;            // k-half

    // ---- one-time: stage Wr rows [i0, i0+16) as exact 3-way bf16 split, swizzled ----
    for (int e = tid * 4; e < 16 * NNEUR; e += 256 * 4) {
        int row = e >> 10;
        int k   = e & 1023;
        float4 wv = *(const float4*)(Wr + (size_t)(i0 + row) * NNEUR + k);
        int ksw = k ^ ((row & 7) << 3);
        float wa[4] = {wv.x, wv.y, wv.z, wv.w};
        #pragma unroll
        for (int j = 0; j < 4; ++j) {
            float fw = wa[j];
            unsigned short hb = f2bf_rn(fw);
            float hf = __uint_as_float((unsigned)hb << 16);
            float rm = fw - hf;
            unsigned short mb = f2bf_rn(rm);
            float mf = __uint_as_float((unsigned)mb << 16);
            float rl = rm - mf;
            unsigned short lb = f2bf_rn(rl);
            wlds[0 * 16384 + row * 1024 + ksw + j] = hb;
            wlds[1 * 16384 + row * 1024 + ksw + j] = mb;
            wlds[2 * 16384 + row * 1024 + ksw + j] = lb;
        }
    }
    __syncthreads();

    const float brv = br[i0 + c];
    float vreg[4] = {0.f, 0.f, 0.f, 0.f};
    const size_t BN = (size_t)BATCH * NNEUR;

    // staging geometry: thread owns rowpair p, cols c0..c0+3
    const int sp_p  = tid >> 4;          // 0..15
    const int sp_c0 = (tid & 15) * 4;    // 0,4,...,60

    for (int t = 0; t < T_STEPS; ++t) {
        float txv[4];
        if (w < 2) {
            #pragma unroll
            for (int j = 0; j < 4; ++j)
                txv[j] = tx[(size_t)t * BN + (size_t)(b0 + w * 16 + kg * 4 + j) * NNEUR + i0 + c];
        }

        // ---- stage spikes of step t-1 into LDS: wide coherent read + stamp verify ----
        if (t > 0) {
            unsigned long long* qb = qbuf + (size_t)((t - 1) % 3) * 4096 + bb * 1024;
            const unsigned want = (unsigned)(t - 1);
            const unsigned long long* a0 = qb + sp_p * 64 + sp_c0;
            uint4v v0, v1;   // [pay0, st0, pay1, st1]
            asm volatile("global_load_dwordx4 %0, %1, off sc0 sc1"
                         : "=&v"(v0) : "v"(a0) : "memory");
            asm volatile("global_load_dwordx4 %0, %1, off sc0 sc1"
                         : "=&v"(v1) : "v"(a0 + 2) : "memory");
            asm volatile("s_waitcnt vmcnt(0)" ::: "memory");
            __builtin_amdgcn_sched_barrier(0);

            unsigned pend = 0;
            {
                if (v0.y == want) { ys[(2*sp_p)*66 + sp_c0+0] = (unsigned short)(v0.x & 0xFFFFu);
                                    ys[(2*sp_p+1)*66 + sp_c0+0] = (unsigned short)(v0.x >> 16); } else pend |= 1u;
                if (v0.w == want) { ys[(2*sp_p)*66 + sp_c0+1] = (unsigned short)(v0.z & 0xFFFFu);
                                    ys[(2*sp_p+1)*66 + sp_c0+1] = (unsigned short)(v0.z >> 16); } else pend |= 2u;
                if (v1.y == want) { ys[(2*sp_p)*66 + sp_c0+2] = (unsigned short)(v1.x & 0xFFFFu);
                                    ys[(2*sp_p+1)*66 + sp_c0+2] = (unsigned short)(v1.x >> 16); } else pend |= 4u;
                if (v1.w == want) { ys[(2*sp_p)*66 + sp_c0+3] = (unsigned short)(v1.z & 0xFFFFu);
                                    ys[(2*sp_p+1)*66 + sp_c0+3] = (unsigned short)(v1.z >> 16); } else pend |= 8u;
            }
            while (pend) {
                #pragma unroll
                for (int k = 0; k < 4; ++k) {
                    if (pend & (1u << k)) {
                        unsigned long long q = __hip_atomic_load(qb + sp_p * 64 + sp_c0 + k,
                                                                 __ATOMIC_RELAXED, __HIP_MEMORY_SCOPE_AGENT);
                        if ((unsigned)(q >> 32) == want) {
                            unsigned pay = (unsigned)q;
                            ys[(2*sp_p)*66 + sp_c0+k]   = (unsigned short)(pay & 0xFFFFu);
                            ys[(2*sp_p+1)*66 + sp_c0+k] = (unsigned short)(pay >> 16);
                            pend &= ~(1u << k);
                        }
                    }
                }
                if (pend) __builtin_amdgcn_s_sleep(1);
            }
        }
        __syncthreads();

        f32x4 acc = {0.f, 0.f, 0.f, 0.f};
        if (t > 0) {
            // A-frags: bf16 1.0 / 0.0 bit patterns (identical to rounds 2/5/6)
            short8 afr[16];
            #pragma unroll
            for (int ks = 0; ks < 16; ++ks) {
                unsigned wv = *(const unsigned*)(ys + (r * 16 + c) * 66 + 2 * (h * 16 + ks));
                unsigned byt = (wv >> (kg * 8)) & 0xFFu;
                FU f;
                #pragma unroll
                for (int q = 0; q < 4; ++q) {
                    f.u[q] = (((byt >> (2 * q)) & 1u) ? 0x00003F80u : 0u)
                           | (((byt >> (2 * q + 1)) & 1u) ? 0x3F800000u : 0u);
                }
                afr[ks] = f.s;
            }
            // single accumulator chain, mat-outer / ks-inner — proven exact order
            #pragma unroll
            for (int mat = 0; mat < 3; ++mat) {
                #pragma unroll
                for (int ks = 0; ks < 16; ++ks) {
                    int kel = h * 512 + ks * 32 + kg * 8;
                    int sw  = kel ^ ((c & 7) << 3);
                    short8 bfr = *(const short8*)(wlds + mat * 16384 + c * 1024 + sw);
                    acc = __builtin_amdgcn_mfma_f32_16x16x32_bf16(afr[ks], bfr, acc, 0, 0, 0);
                }
            }
        }

        if (w >= 2) {
            #pragma unroll
            for (int j = 0; j < 4; ++j)
                red[r * 256 + (kg * 4 + j) * 16 + c] = acc[j];
        }
        __syncthreads();

        if (w < 2) {
            float* op = out + (size_t)t * BN;
            unsigned long long* pb = qbuf + (size_t)(t % 3) * 4096 + bb * 1024;
            unsigned long long mball[4];
            #pragma unroll
            for (int j = 0; j < 4; ++j) {
                float z  = acc[j] + red[w * 256 + (kg * 4 + j) * 16 + c];
                float x  = (txv[j] + z) + brv;
                float vv = DECAY_F * vreg[j] + x;
                int   sp = vv > THRESH;
                vreg[j]  = sp ? 0.f : vv;
                op[(size_t)(b0 + w * 16 + kg * 4 + j) * NNEUR + i0 + c] = sp ? 1.f : 0.f;
                mball[j] = __ballot(sp != 0);
            }
            // publish rowpairs: lanes c==0 (a=0) and c==2 (a=1) of each kg
            if (c == 0 || c == 2) {
                int a = c >> 1;
                unsigned lo = (unsigned)((mball[2*a]     >> (kg * 16)) & 0xFFFFu);
                unsigned hi = (unsigned)((mball[2*a + 1] >> (kg * 16)) & 0xFFFFu);
                unsigned long long q = ((unsigned long long)(unsigned)t << 32)
                                     | ((unsigned long long)hi << 16) | lo;
                int pp = w * 8 + kg * 2 + a;   // rowpair index within group
                atomicExch(pb + pp * 64 + ib, q);
            }
        }
        // no end-of-step barrier: stamp polling is the synchronization
    }
}

extern "C" void kernel_launch(void* const* d_in, const int* in_sizes, int n_in,
                              void* d_out, int out_size, void* d_ws, size_t ws_size,
                              hipStream_t stream)
{
    const float* tx = (const float*)d_in[0];
    const float* Wr = (const float*)d_in[1];
    const float* br = (const float*)d_in[2];
    float* out = (float*)d_out;
    unsigned long long* qbuf = (unsigned long long*)d_ws;   // [3][64][64] u64 = 96 KB

    const int lds_bytes = 3 * 16 * 1024 * 2 + 2 * 16 * 16 * 4 + 32 * 66 * 2;  // 103552
    hipFuncSetAttribute(reinterpret_cast<const void*>(rlif_persist),
                        hipFuncAttributeMaxDynamicSharedMemorySize, lds_bytes);

    rlif_init<<<dim3(48), dim3(256), 0, stream>>>(qbuf);
    rlif_persist<<<dim3(256), dim3(256), lds_bytes, stream>>>(tx, Wr, br, out, qbuf);
}

// Round 8
// 1586.980 us; speedup vs baseline: 1.0488x; 1.0488x over previous
//
#include <hip/hip_runtime.h>

// RLIF forward, persistent kernel, stamp-in-word sync.
// Round 8 vs round 6 (PASS @1354us), two surgical changes:
//  1. Batched poll: each thread reloads its 4 u64 qwords (8 stamped u32 words)
//     UNCONDITIONALLY per round -> 4 independent loads, one waitcnt, then checks.
//     (Rounds 5/6 guarded each load with a dependent branch -> 8 serialized LLC
//     roundtrips ~3-4us/step. That was the hidden cost, not volume: round 7
//     cut volume 16x and regressed.)
//  2. Publish-first epilogue: ballot+atomicExch before the out stores.
// Datapath (Wr 3-split, MFMA chain order, epilogue arithmetic) frozen = round 6.

#define T_STEPS 256
#define BATCH   128
#define NNEUR   1024
#define DECAY_F 0.2f
#define THRESH  0.3f

typedef __attribute__((ext_vector_type(8))) short short8;
typedef __attribute__((ext_vector_type(4))) float f32x4;

union FU { short8 s; unsigned u[4]; };

__device__ __forceinline__ unsigned short f2bf_rn(float x) {
    unsigned u = __float_as_uint(x);
    return (unsigned short)((u + 0x7FFFu + ((u >> 16) & 1u)) >> 16);
}

__global__ void rlif_init(unsigned* __restrict__ ybits) {
    int i = blockIdx.x * 256 + threadIdx.x;
    if (i < 3 * BATCH * 64) ybits[i] = 0xFFFF0000u;   // stamp 0xFFFF: never matches t
}

__global__ __launch_bounds__(256, 1)
void rlif_persist(const float* __restrict__ tx,   // [T][B][N]
                  const float* __restrict__ Wr,   // [N][N]
                  const float* __restrict__ br,   // [N]
                  float* __restrict__ out,        // [T][B][N]
                  unsigned* __restrict__ ybits)   // [3][128][64] stamped words
{
    extern __shared__ char smem[];
    unsigned short* wlds = (unsigned short*)smem;        // 3 * [16][1024] bf16, swizzled
    float* red = (float*)(smem + 3 * 16 * 1024 * 2);     // [2][16][16] f32 k-reduce
    unsigned short* ys = (unsigned short*)(smem + 3 * 16 * 1024 * 2 + 2 * 16 * 16 * 4); // [32][66]

    const int tid = threadIdx.x;
    const int bb  = blockIdx.x >> 6;   // 0..3  batch-block (32 batches)
    const int ib  = blockIdx.x & 63;   // 0..63 neuron-block (16 neurons)
    const int i0  = ib * 16;
    const int b0  = bb * 32;
    const int w   = tid >> 6;          // wave 0..3
    const int l   = tid & 63;
    const int c   = l & 15;
    const int kg  = l >> 4;
    const int r   = w & 1;             // row-tile
    const int h   = w >> 1;            // k-half

    // ---- one-time: stage Wr rows [i0, i0+16) as exact 3-way bf16 split, swizzled ----
    for (int e = tid * 4; e < 16 * NNEUR; e += 256 * 4) {
        int row = e >> 10;
        int k   = e & 1023;
        float4 wv = *(const float4*)(Wr + (size_t)(i0 + row) * NNEUR + k);
        int ksw = k ^ ((row & 7) << 3);
        float wa[4] = {wv.x, wv.y, wv.z, wv.w};
        #pragma unroll
        for (int j = 0; j < 4; ++j) {
            float fw = wa[j];
            unsigned short hb = f2bf_rn(fw);
            float hf = __uint_as_float((unsigned)hb << 16);
            float rm = fw - hf;
            unsigned short mb = f2bf_rn(rm);
            float mf = __uint_as_float((unsigned)mb << 16);
            float rl = rm - mf;
            unsigned short lb = f2bf_rn(rl);
            wlds[0 * 16384 + row * 1024 + ksw + j] = hb;
            wlds[1 * 16384 + row * 1024 + ksw + j] = mb;
            wlds[2 * 16384 + row * 1024 + ksw + j] = lb;
        }
    }
    __syncthreads();

    const float brv = br[i0 + c];
    float vreg[4] = {0.f, 0.f, 0.f, 0.f};
    const size_t BN = (size_t)BATCH * NNEUR;

    // poll geometry: thread owns col-pair cp, rows rb, rb+8, rb+16, rb+24
    const int cp = tid & 31;
    const int rb = tid >> 5;

    for (int t = 0; t < T_STEPS; ++t) {
        float txv[4];
        if (w < 2) {
            #pragma unroll
            for (int j = 0; j < 4; ++j)
                txv[j] = tx[(size_t)t * BN + (size_t)(b0 + w * 16 + kg * 4 + j) * NNEUR + i0 + c];
        }

        // ---- stage spikes of step t-1 into LDS: batched stamped-qword poll ----
        if (t > 0) {
            unsigned long long* qb64 =
                (unsigned long long*)(ybits + (size_t)((t - 1) % 3) * (BATCH * 64));
            const unsigned want = (unsigned)(t - 1);
            unsigned pend = 0xFu;
            while (pend) {
                unsigned long long qv[4];
                #pragma unroll
                for (int k = 0; k < 4; ++k)
                    qv[k] = __hip_atomic_load(qb64 + (size_t)(b0 + rb + 8 * k) * 32 + cp,
                                              __ATOMIC_RELAXED, __HIP_MEMORY_SCOPE_AGENT);
                #pragma unroll
                for (int k = 0; k < 4; ++k) {
                    if (pend & (1u << k)) {
                        unsigned lo = (unsigned)qv[k];
                        unsigned hi = (unsigned)(qv[k] >> 32);
                        if (((lo >> 16) == want) & ((hi >> 16) == want)) {
                            *(unsigned*)&ys[(rb + 8 * k) * 66 + 2 * cp] =
                                (lo & 0xFFFFu) | (hi << 16);
                            pend &= ~(1u << k);
                        }
                    }
                }
            }
        }
        __syncthreads();

        f32x4 acc = {0.f, 0.f, 0.f, 0.f};
        if (t > 0) {
            // A-frags: bf16 1.0 / 0.0 bit patterns (identical to rounds 2/5/6)
            short8 afr[16];
            #pragma unroll
            for (int ks = 0; ks < 16; ++ks) {
                unsigned wv = *(const unsigned*)(ys + (r * 16 + c) * 66 + 2 * (h * 16 + ks));
                unsigned byt = (wv >> (kg * 8)) & 0xFFu;
                FU f;
                #pragma unroll
                for (int q = 0; q < 4; ++q) {
                    f.u[q] = (((byt >> (2 * q)) & 1u) ? 0x00003F80u : 0u)
                           | (((byt >> (2 * q + 1)) & 1u) ? 0x3F800000u : 0u);
                }
                afr[ks] = f.s;
            }
            // single accumulator chain, mat-outer / ks-inner — proven exact order
            #pragma unroll
            for (int mat = 0; mat < 3; ++mat) {
                #pragma unroll
                for (int ks = 0; ks < 16; ++ks) {
                    int kel = h * 512 + ks * 32 + kg * 8;
                    int sw  = kel ^ ((c & 7) << 3);
                    short8 bfr = *(const short8*)(wlds + mat * 16384 + c * 1024 + sw);
                    acc = __builtin_amdgcn_mfma_f32_16x16x32_bf16(afr[ks], bfr, acc, 0, 0, 0);
                }
            }
        }

        if (w >= 2) {
            #pragma unroll
            for (int j = 0; j < 4; ++j)
                red[r * 256 + (kg * 4 + j) * 16 + c] = acc[j];
        }
        __syncthreads();

        if (w < 2) {
            float* op = out + (size_t)t * BN;
            unsigned* pbuf = ybits + (size_t)(t % 3) * (BATCH * 64);
            int   sp4[4];
            unsigned long long mball[4];
            #pragma unroll
            for (int j = 0; j < 4; ++j) {
                float z  = acc[j] + red[w * 256 + (kg * 4 + j) * 16 + c];
                float x  = (txv[j] + z) + brv;
                float vv = DECAY_F * vreg[j] + x;
                int   sp = vv > THRESH;
                vreg[j]  = sp ? 0.f : vv;
                sp4[j]   = sp;
                mball[j] = __ballot(sp != 0);
            }
            // publish FIRST (critical path: peers poll these words)
            #pragma unroll
            for (int j = 0; j < 4; ++j) {
                if (c == j) {
                    unsigned u16v = (unsigned)((mball[j] >> (kg * 16)) & 0xFFFFu);
                    atomicExch(&pbuf[(b0 + w * 16 + kg * 4 + j) * 64 + ib],
                               ((unsigned)t << 16) | u16v);
                }
            }
            // then the out-slab stores (no intra-kernel consumer)
            #pragma unroll
            for (int j = 0; j < 4; ++j)
                op[(size_t)(b0 + w * 16 + kg * 4 + j) * NNEUR + i0 + c] = sp4[j] ? 1.f : 0.f;
        }
        // no end-of-step barrier: stamp polling is the synchronization
    }
}

extern "C" void kernel_launch(void* const* d_in, const int* in_sizes, int n_in,
                              void* d_out, int out_size, void* d_ws, size_t ws_size,
                              hipStream_t stream)
{
    const float* tx = (const float*)d_in[0];
    const float* Wr = (const float*)d_in[1];
    const float* br = (const float*)d_in[2];
    float* out = (float*)d_out;
    unsigned* ybits = (unsigned*)d_ws;   // [3][128][64] u32 = 96 KB

    const int lds_bytes = 3 * 16 * 1024 * 2 + 2 * 16 * 16 * 4 + 32 * 66 * 2;  // 103552
    hipFuncSetAttribute(reinterpret_cast<const void*>(rlif_persist),
                        hipFuncAttributeMaxDynamicSharedMemorySize, lds_bytes);

    rlif_init<<<dim3(96), dim3(256), 0, stream>>>(ybits);
    rlif_persist<<<dim3(256), dim3(256), lds_bytes, stream>>>(tx, Wr, br, out, ybits);
}

// Round 10
// 1576.274 us; speedup vs baseline: 1.0559x; 1.0068x over previous
//
#include <hip/hip_runtime.h>

// RLIF forward, persistent kernel, stamp-in-word sync.
// Round 10 = Round 8 (PASS @1587us, fully validated incl. post-timing) plus
// EXACTLY ONE change: s_sleep(1) backoff between batched poll rounds.
//   R6: serialized guarded loads + sleep  -> 1354us (8 LLC RTTs per round)
//   R8: batched parallel loads, hot spin  -> 1587us (+80MB FETCH: poll storm
//       saturates the LLC path the publishes themselves must traverse)
//   R10: batched parallel loads + sleep   -> tests the last untested cell.
// Datapath (Wr 3-split, ys layout, single MFMA chain, epilogue) frozen = R6/R8.

#define T_STEPS 256
#define BATCH   128
#define NNEUR   1024
#define DECAY_F 0.2f
#define THRESH  0.3f

typedef __attribute__((ext_vector_type(8))) short short8;
typedef __attribute__((ext_vector_type(4))) float f32x4;

union FU { short8 s; unsigned u[4]; };

__device__ __forceinline__ unsigned short f2bf_rn(float x) {
    unsigned u = __float_as_uint(x);
    return (unsigned short)((u + 0x7FFFu + ((u >> 16) & 1u)) >> 16);
}

__global__ void rlif_init(unsigned* __restrict__ ybits) {
    int i = blockIdx.x * 256 + threadIdx.x;
    if (i < 3 * BATCH * 64) ybits[i] = 0xFFFF0000u;   // stamp 0xFFFF: never matches t
}

__global__ __launch_bounds__(256, 1)
void rlif_persist(const float* __restrict__ tx,   // [T][B][N]
                  const float* __restrict__ Wr,   // [N][N]
                  const float* __restrict__ br,   // [N]
                  float* __restrict__ out,        // [T][B][N]
                  unsigned* __restrict__ ybits)   // [3][128][64] stamped words
{
    extern __shared__ char smem[];
    unsigned short* wlds = (unsigned short*)smem;        // 3 * [16][1024] bf16, swizzled
    float* red = (float*)(smem + 3 * 16 * 1024 * 2);     // [2][16][16] f32 k-reduce
    unsigned short* ys = (unsigned short*)(smem + 3 * 16 * 1024 * 2 + 2 * 16 * 16 * 4); // [32][66]

    const int tid = threadIdx.x;
    const int bb  = blockIdx.x >> 6;   // 0..3  batch-block (32 batches)
    const int ib  = blockIdx.x & 63;   // 0..63 neuron-block (16 neurons)
    const int i0  = ib * 16;
    const int b0  = bb * 32;
    const int w   = tid >> 6;          // wave 0..3
    const int l   = tid & 63;
    const int c   = l & 15;
    const int kg  = l >> 4;
    const int r   = w & 1;             // row-tile
    const int h   = w >> 1;            // k-half

    // ---- one-time: stage Wr rows [i0, i0+16) as exact 3-way bf16 split, swizzled ----
    for (int e = tid * 4; e < 16 * NNEUR; e += 256 * 4) {
        int row = e >> 10;
        int k   = e & 1023;
        float4 wv = *(const float4*)(Wr + (size_t)(i0 + row) * NNEUR + k);
        int ksw = k ^ ((row & 7) << 3);
        float wa[4] = {wv.x, wv.y, wv.z, wv.w};
        #pragma unroll
        for (int j = 0; j < 4; ++j) {
            float fw = wa[j];
            unsigned short hb = f2bf_rn(fw);
            float hf = __uint_as_float((unsigned)hb << 16);
            float rm = fw - hf;
            unsigned short mb = f2bf_rn(rm);
            float mf = __uint_as_float((unsigned)mb << 16);
            float rl = rm - mf;
            unsigned short lb = f2bf_rn(rl);
            wlds[0 * 16384 + row * 1024 + ksw + j] = hb;
            wlds[1 * 16384 + row * 1024 + ksw + j] = mb;
            wlds[2 * 16384 + row * 1024 + ksw + j] = lb;
        }
    }
    __syncthreads();

    const float brv = br[i0 + c];
    float vreg[4] = {0.f, 0.f, 0.f, 0.f};
    const size_t BN = (size_t)BATCH * NNEUR;

    // poll geometry: thread owns col-pair cp, rows rb, rb+8, rb+16, rb+24
    const int cp = tid & 31;
    const int rb = tid >> 5;

    for (int t = 0; t < T_STEPS; ++t) {
        float txv[4];
        if (w < 2) {
            #pragma unroll
            for (int j = 0; j < 4; ++j)
                txv[j] = tx[(size_t)t * BN + (size_t)(b0 + w * 16 + kg * 4 + j) * NNEUR + i0 + c];
        }

        // ---- stage spikes of step t-1 into LDS: batched stamped-qword poll + backoff ----
        if (t > 0) {
            unsigned long long* qb64 =
                (unsigned long long*)(ybits + (size_t)((t - 1) % 3) * (BATCH * 64));
            const unsigned want = (unsigned)(t - 1);
            unsigned pend = 0xFu;
            for (;;) {
                unsigned long long qv[4];
                #pragma unroll
                for (int k = 0; k < 4; ++k)
                    qv[k] = __hip_atomic_load(qb64 + (size_t)(b0 + rb + 8 * k) * 32 + cp,
                                              __ATOMIC_RELAXED, __HIP_MEMORY_SCOPE_AGENT);
                #pragma unroll
                for (int k = 0; k < 4; ++k) {
                    if (pend & (1u << k)) {
                        unsigned lo = (unsigned)qv[k];
                        unsigned hi = (unsigned)(qv[k] >> 32);
                        if (((lo >> 16) == want) & ((hi >> 16) == want)) {
                            *(unsigned*)&ys[(rb + 8 * k) * 66 + 2 * cp] =
                                (lo & 0xFFFFu) | (hi << 16);
                            pend &= ~(1u << k);
                        }
                    }
                }
                if (!pend) break;
                __builtin_amdgcn_s_sleep(1);   // the one change vs round 8
            }
        }
        __syncthreads();

        f32x4 acc = {0.f, 0.f, 0.f, 0.f};
        if (t > 0) {
            // A-frags: bf16 1.0 / 0.0 bit patterns (identical to rounds 2/5/6/8)
            short8 afr[16];
            #pragma unroll
            for (int ks = 0; ks < 16; ++ks) {
                unsigned wv = *(const unsigned*)(ys + (r * 16 + c) * 66 + 2 * (h * 16 + ks));
                unsigned byt = (wv >> (kg * 8)) & 0xFFu;
                FU f;
                #pragma unroll
                for (int q = 0; q < 4; ++q) {
                    f.u[q] = (((byt >> (2 * q)) & 1u) ? 0x00003F80u : 0u)
                           | (((byt >> (2 * q + 1)) & 1u) ? 0x3F800000u : 0u);
                }
                afr[ks] = f.s;
            }
            // single accumulator chain, mat-outer / ks-inner — proven exact order
            #pragma unroll
            for (int mat = 0; mat < 3; ++mat) {
                #pragma unroll
                for (int ks = 0; ks < 16; ++ks) {
                    int kel = h * 512 + ks * 32 + kg * 8;
                    int sw  = kel ^ ((c & 7) << 3);
                    short8 bfr = *(const short8*)(wlds + mat * 16384 + c * 1024 + sw);
                    acc = __builtin_amdgcn_mfma_f32_16x16x32_bf16(afr[ks], bfr, acc, 0, 0, 0);
                }
            }
        }

        if (w >= 2) {
            #pragma unroll
            for (int j = 0; j < 4; ++j)
                red[r * 256 + (kg * 4 + j) * 16 + c] = acc[j];
        }
        __syncthreads();

        if (w < 2) {
            float* op = out + (size_t)t * BN;
            unsigned* pbuf = ybits + (size_t)(t % 3) * (BATCH * 64);
            int   sp4[4];
            unsigned long long mball[4];
            #pragma unroll
            for (int j = 0; j < 4; ++j) {
                float z  = acc[j] + red[w * 256 + (kg * 4 + j) * 16 + c];
                float x  = (txv[j] + z) + brv;
                float vv = DECAY_F * vreg[j] + x;
                int   sp = vv > THRESH;
                vreg[j]  = sp ? 0.f : vv;
                sp4[j]   = sp;
                mball[j] = __ballot(sp != 0);
            }
            // publish FIRST (critical path: peers poll these words)
            #pragma unroll
            for (int j = 0; j < 4; ++j) {
                if (c == j) {
                    unsigned u16v = (unsigned)((mball[j] >> (kg * 16)) & 0xFFFFu);
                    atomicExch(&pbuf[(b0 + w * 16 + kg * 4 + j) * 64 + ib],
                               ((unsigned)t << 16) | u16v);
                }
            }
            // then the out-slab stores (no intra-kernel consumer)
            #pragma unroll
            for (int j = 0; j < 4; ++j)
                op[(size_t)(b0 + w * 16 + kg * 4 + j) * NNEUR + i0 + c] = sp4[j] ? 1.f : 0.f;
        }
        // no end-of-step barrier: stamp polling is the synchronization
    }
}

extern "C" void kernel_launch(void* const* d_in, const int* in_sizes, int n_in,
                              void* d_out, int out_size, void* d_ws, size_t ws_size,
                              hipStream_t stream)
{
    const float* tx = (const float*)d_in[0];
    const float* Wr = (const float*)d_in[1];
    const float* br = (const float*)d_in[2];
    float* out = (float*)d_out;
    unsigned* ybits = (unsigned*)d_ws;   // [3][128][64] u32 = 96 KB

    const int lds_bytes = 3 * 16 * 1024 * 2 + 2 * 16 * 16 * 4 + 32 * 66 * 2;  // 103552
    hipFuncSetAttribute(reinterpret_cast<const void*>(rlif_persist),
                        hipFuncAttributeMaxDynamicSharedMemorySize, lds_bytes);

    rlif_init<<<dim3(96), dim3(256), 0, stream>>>(ybits);
    rlif_persist<<<dim3(256), dim3(256), lds_bytes, stream>>>(tx, Wr, br, out, ybits);
}